// Round 17
// baseline (426.092 us; speedup 1.0000x reference)
//
#include <hip/hip_runtime.h>
#include <math.h>

#define BB 8
#define CC 256
#define NTOK 2304   // 48*48
#define NPL 36      // 32-token pairs per k-half (split-K factor 2)
#define LOG2E 1.4426950408889634f
#define BIAS2 72.134752f   // p = 2^(s-BIAS2): overflow-free no-max softmax

typedef __attribute__((ext_vector_type(4))) float f32x4;
typedef __attribute__((ext_vector_type(8))) short s16x8;
typedef __attribute__((ext_vector_type(4))) short s16x4;

__device__ inline unsigned short f2bf(float x) {
  unsigned u = __builtin_bit_cast(unsigned, x);
  return (unsigned short)((u + 0x7FFFu + ((u >> 16) & 1u)) >> 16);
}
__device__ inline float bf2f(unsigned short h) {
  return __builtin_bit_cast(float, (unsigned)h << 16);
}
__device__ inline unsigned short f2h(float x) {
  _Float16 h = (_Float16)x;
  return __builtin_bit_cast(unsigned short, h);
}

// async global -> LDS, 16B/lane; LDS dst = wave-uniform base + lane*16
__device__ inline void async16(void* lds, const void* g) {
  __builtin_amdgcn_global_load_lds(
      (const __attribute__((address_space(1))) unsigned int*)g,
      (__attribute__((address_space(3))) unsigned int*)lds, 16, 0, 0);
}

// ---------------- prepass: X[c][n] fp32 -> Xt[n][c] fp16 (z<24); W conv (z==24) ----------------
__global__ __launch_bounds__(256)
void prep_kernel(const float* __restrict__ X0, const float* __restrict__ X1,
                 const float* __restrict__ X2, unsigned short* __restrict__ Y0,
                 unsigned short* __restrict__ Y1, unsigned short* __restrict__ Y2,
                 const float* __restrict__ W0, const float* __restrict__ W1,
                 const float* __restrict__ W2, unsigned short* __restrict__ Wh0,
                 unsigned short* __restrict__ Wh1, unsigned short* __restrict__ Wh2) {
  __shared__ float Ls[64][65];
  const int t = threadIdx.x;
  const int z = blockIdx.z;

  if (z == 24) {
    int idx = (blockIdx.x * 4 + blockIdx.y) * 256 + t;     // 0..36863
    for (int e = idx; e < 49152; e += 36864) {
      int m = e / 16384, r = e - m * 16384;
      const float* s = (m == 0) ? W0 : (m == 1) ? W1 : W2;
      unsigned short* d = (m == 0) ? Wh0 : (m == 1) ? Wh1 : Wh2;
      f32x4 v = *(const f32x4*)(s + r * 4);
      s16x4 o;
      #pragma unroll
      for (int i = 0; i < 4; i++) o[i] = (short)f2h(v[i]);
      *(s16x4*)(d + r * 4) = o;
    }
    return;
  }

  const int n0 = blockIdx.x * 64, c0 = blockIdx.y * 64;
  const int src = z >> 3, b = z & 7;
  const float* X = (src == 0) ? X0 : (src == 1) ? X1 : X2;
  unsigned short* Y = (src == 0) ? Y0 : (src == 1) ? Y1 : Y2;
  const float* Xb = X + (size_t)b * CC * NTOK;
  unsigned short* Yb = Y + (size_t)b * CC * NTOK;

  #pragma unroll
  for (int rr = 0; rr < 16; rr++) {
    int cl = rr * 4 + (t >> 6);
    Ls[cl][t & 63] = Xb[(size_t)(c0 + cl) * NTOK + n0 + (t & 63)];
  }
  __syncthreads();
  #pragma unroll
  for (int rr = 0; rr < 8; rr++) {
    int nl = rr * 8 + (t >> 5);
    int cl = (t & 31) * 2;
    unsigned v = (unsigned)f2h(Ls[cl][nl]) | ((unsigned)f2h(Ls[cl + 1][nl]) << 16);
    *(unsigned*)((char*)Yb + ((size_t)(n0 + nl) * CC + c0 + cl) * 2) = v;
  }
}

// ---------------- fused MFMA projection GEMM (all 4 projections, one dispatch) ----------------
__global__ __launch_bounds__(256, 2)
void gemm_kernel(const unsigned short* __restrict__ Xtq, const unsigned short* __restrict__ Xtm,
                 const unsigned short* __restrict__ Xtf, const unsigned short* __restrict__ Wqh,
                 const unsigned short* __restrict__ Wkh, const unsigned short* __restrict__ Wvh,
                 unsigned short* __restrict__ Qw, unsigned short* __restrict__ K1w,
                 unsigned short* __restrict__ K2w, unsigned short* __restrict__ Vtw) {
  __shared__ alignas(16) char smem[32768];

  const int m = blockIdx.y;
  const unsigned short* Xt = (m == 0) ? Xtq : (m == 2) ? Xtm : Xtf;
  const unsigned short* Wh = (m == 0) ? Wqh : (m == 3) ? Wvh : Wkh;
  unsigned short* Y = (m == 0) ? Qw : (m == 1) ? K1w : (m == 2) ? K2w : Vtw;

  const int t = threadIdx.x;
  const int w = t >> 6, l = t & 63, g = l >> 4, c = l & 15;
  const int bid = blockIdx.x;
  const int b = bid & 7, nt = bid >> 3;
  const int n0w = nt * 64 + w * 16;
  const size_t bo = (size_t)b * CC * NTOK;

  const char* Xb = (const char*)(Xt + bo);
  const char* Wb = (const char*)Wh;
  char* Yb = (char*)(Y + bo);

  int koff[4], cdst[4];
  #pragma unroll
  for (int j = 0; j < 4; j++) {
    int ck = w + 4 * j;
    int row = ck * 2 + (l >> 5);
    koff[j] = row * 512 + (((l & 31) * 16) ^ ((row & 7) << 4));
    cdst[j] = ck * 1024 + l * 16;
  }
  int kxor[8];
  #pragma unroll
  for (int dc = 0; dc < 8; dc++)
    kxor[dc] = (dc * 64 + g * 16) ^ ((c & 7) << 4);

  s16x8 xa[8];
  #pragma unroll
  for (int dc = 0; dc < 8; dc++)
    xa[dc] = *(const s16x8*)(Xb + (n0w + c) * 512 + dc * 64 + g * 16);

  f32x4 acc[16];

#define STAGE_W(WB, TILE)                                            \
  do {                                                               \
    _Pragma("unroll")                                                \
    for (int j_ = 0; j_ < 4; j_++)                                   \
      async16((WB) + cdst[j_], Wb + (TILE) * 16384 + koff[j_]);      \
  } while (0)

  STAGE_W(smem, 0);
  __syncthreads();

  #pragma unroll
  for (int ph = 0; ph < 8; ph++) {
    char* cur = smem + (ph & 1) * 16384;
    if (ph < 7) STAGE_W(smem + ((ph & 1) ^ 1) * 16384, ph + 1);
    __builtin_amdgcn_s_setprio(1);
    #pragma unroll
    for (int s = 0; s < 2; s++) {
      const char* Kt = cur + (s * 16 + c) * 512;
      f32x4 sx[2] = {(f32x4){0.f, 0.f, 0.f, 0.f}, (f32x4){0.f, 0.f, 0.f, 0.f}};
      #pragma unroll
      for (int dc = 0; dc < 8; dc++) {
        s16x8 wf = *(const s16x8*)(Kt + kxor[dc]);
        sx[dc >> 2] = __builtin_amdgcn_mfma_f32_16x16x32_f16(xa[dc], wf, sx[dc >> 2], 0, 0, 0);
      }
      acc[ph * 2 + s] = sx[0] + sx[1];
    }
    __builtin_amdgcn_s_setprio(0);
    __syncthreads();
  }
#undef STAGE_W

  if (m != 3) {
    unsigned short* Ws = (unsigned short*)(smem + w * 8192);   // [16][256]
    const float scale = (m == 0) ? LOG2E : 1.0f;
    #pragma unroll
    for (int dt = 0; dt < 16; dt++)
      #pragma unroll
      for (int j = 0; j < 4; j++)
        Ws[(g * 4 + j) * 256 + dt * 16 + c] = f2h(acc[dt][j] * scale);
    #pragma unroll
    for (int r = 0; r < 16; r++) {
      s16x4 v = *(const s16x4*)&Ws[r * 256 + l * 4];
      *(s16x4*)(Yb + (size_t)(n0w + r) * 512 + l * 8) = v;
    }
  } else {
    unsigned short* Vs = (unsigned short*)(smem + w * 8192);   // [16][20]
    #pragma unroll
    for (int dt = 0; dt < 16; dt++) {
      s16x4 pv;
      #pragma unroll
      for (int j = 0; j < 4; j++) pv[j] = (short)f2bf(acc[dt][j]);
      *(s16x4*)&Vs[c * 20 + g * 4] = pv;
      s16x4 vv = *(const s16x4*)&Vs[(l >> 2) * 20 + (l & 3) * 4];
      *(s16x4*)(Yb + (size_t)(dt * 16 + (l >> 2)) * 4608 + (size_t)(n0w + (l & 3) * 4) * 2) = vv;
    }
  }
}

// ---------------- attention: 8 waves x (1 path x 16 q-rows), 4 waves/SIMD target ----------------
// Same phase/barrier/staging schedule as R16 (L2-pacing-safe). Per-wave state
// halved (acc 64 + qf 32 VGPR) -> __launch_bounds__(512,4) forces <=128 VGPR
// -> 2 blocks/CU x 8 waves = 4 waves/SIMD (double R16's occupancy).
__global__ __launch_bounds__(512, 4)
void attn_kernel(const unsigned short* __restrict__ Qf, const unsigned short* __restrict__ K1,
                 const unsigned short* __restrict__ K2, const unsigned short* __restrict__ Vt,
                 unsigned short* __restrict__ pa1, unsigned short* __restrict__ pa2,
                 float* __restrict__ lb) {
  // kb0@0 kb1@16384 (each K1 8K | K2 8K) | vb@32768: 2 x 16K | P@65536: 8 x 1536
  __shared__ alignas(16) char smem[77824];
  char* const kb0 = smem;
  char* const kb1 = smem + 16384;

  const int t = threadIdx.x;
  const int w = t >> 6, l = t & 63, g = l >> 4, c = l & 15;
  const int path = w >> 2, qs = w & 3;      // 2 paths x 4 q-strips of 16 rows
  const int bid = blockIdx.x;
  const int b = bid & 7;                    // batch -> XCD pin
  const int r0 = bid >> 3;                  // 0..71
  const int qt = r0 % 36, half = r0 / 36;
  const int q0 = qt * 64 + qs * 16;         // this wave's 16 q-rows
  const size_t bo = (size_t)b * CC * NTOK;

  const char* Qb  = (const char*)(Qf + bo);
  const char* K1b = (const char*)(K1 + bo);
  const char* K2b = (const char*)(K2 + bo);
  const char* Vtb = (const char*)(Vt + bo);

  unsigned short* const Pe  = (unsigned short*)(smem + 65536 + w * 1536);  // [16][24]
  unsigned short* const Pod = Pe + 384;

  // staging: 512 threads, 1 chunk/region each. rid = w*64 + l.
  const int rid = w * 64 + l;
  const int ktok = rid >> 5;                               // 0..15
  const int koff = ktok * 512 + (((rid & 31) * 16) ^ ((ktok & 7) << 4));
  const int vrow = rid >> 1;                               // 0..255
  const int voff = vrow * 4608 + 16 * ((rid & 1) ^ ((rid >> 3) & 1));
  const int cdst = rid * 16;

  int kxor[8];
  #pragma unroll
  for (int dc = 0; dc < 8; dc++)
    kxor[dc] = (dc * 64 + g * 16) ^ ((c & 7) << 4);

  // Q fp16 fragments: 8 dc (16 q-rows)
  s16x8 qf[8];
  #pragma unroll
  for (int dc = 0; dc < 8; dc++)
    qf[dc] = *(const s16x8*)(Qb + (q0 + c) * 512 + dc * 64 + g * 16);

  f32x4 acc[16];
  #pragma unroll
  for (int dt = 0; dt < 16; dt++)
    acc[dt] = (f32x4){0.f, 0.f, 0.f, 0.f};
  float lr[4] = {0.f, 0.f, 0.f, 0.f};

#define STAGE_K(KB, TILE)                                                  \
  do {                                                                     \
    async16((KB) + cdst, K1b + (size_t)(TILE) * 8192 + koff);              \
    async16((KB) + 8192 + cdst, K2b + (size_t)(TILE) * 8192 + koff);       \
  } while (0)

#define STAGE_V(VB, PAIR)                                                  \
  do {                                                                     \
    async16((VB) + cdst, Vtb + (size_t)(PAIR) * 64 + voff);                \
    async16((VB) + 8192 + cdst, Vtb + (size_t)(PAIR) * 64 + 32 + voff);    \
  } while (0)

  const int tb = half * 72;                 // k-tile base for this half
  const int pb = half * 36;                 // V pair base

  STAGE_K(kb0, tb);
  STAGE_V(smem + 32768, pb);
  __syncthreads();

  for (int p = 0; p < NPL; p++) {
    char* vcur = smem + 32768 + (p & 1) * 16384;
    char* vnxt = smem + 32768 + ((p & 1) ^ 1) * 16384;

    // ======== even phase: tile tb+2p from kb0 (this wave's path) ========
    STAGE_K(kb1, tb + 2 * p + 1);
    {
      const char* Kt = kb0 + path * 8192 + c * 512;
      f32x4 sx0 = (f32x4){0.f, 0.f, 0.f, 0.f};
      f32x4 sx1 = (f32x4){0.f, 0.f, 0.f, 0.f};
      __builtin_amdgcn_s_setprio(1);
      #pragma unroll
      for (int dc = 0; dc < 8; dc++) {
        s16x8 kf = *(const s16x8*)(Kt + kxor[dc]);
        if (dc < 4) sx0 = __builtin_amdgcn_mfma_f32_16x16x32_f16(qf[dc], kf, sx0, 0, 0, 0);
        else        sx1 = __builtin_amdgcn_mfma_f32_16x16x32_f16(qf[dc], kf, sx1, 0, 0, 0);
      }
      __builtin_amdgcn_s_setprio(0);
      f32x4 s = sx0 + sx1;
      #pragma unroll
      for (int j = 0; j < 4; j++) {
        float pv = exp2f(s[j] - BIAS2);
        lr[j] += pv;
        Pe[(g * 4 + j) * 24 + c] = f2bf(pv);
      }
    }
    __syncthreads();

    // ======== odd phase: tile tb+2p+1 from kb1, PV on vcur ========
    if (p + 1 < NPL) {
      STAGE_K(kb0, tb + 2 * p + 2);
      STAGE_V(vnxt, pb + p + 1);
    }
    {
      const char* Kt = kb1 + path * 8192 + c * 512;
      f32x4 sx0 = (f32x4){0.f, 0.f, 0.f, 0.f};
      f32x4 sx1 = (f32x4){0.f, 0.f, 0.f, 0.f};
      __builtin_amdgcn_s_setprio(1);
      #pragma unroll
      for (int dc = 0; dc < 8; dc++) {
        s16x8 kf = *(const s16x8*)(Kt + kxor[dc]);
        if (dc < 4) sx0 = __builtin_amdgcn_mfma_f32_16x16x32_f16(qf[dc], kf, sx0, 0, 0, 0);
        else        sx1 = __builtin_amdgcn_mfma_f32_16x16x32_f16(qf[dc], kf, sx1, 0, 0, 0);
      }
      __builtin_amdgcn_s_setprio(0);
      f32x4 s = sx0 + sx1;
      #pragma unroll
      for (int j = 0; j < 4; j++) {
        float pv = exp2f(s[j] - BIAS2);
        lr[j] += pv;
        Pod[(g * 4 + j) * 24 + c] = f2bf(pv);
      }
    }
    {
      // paired A-frag (K=32): g<2 lanes -> even-tile P, g>=2 -> odd-tile P
      s16x8 pa = *(const s16x8*)(((g < 2) ? Pe : Pod) + c * 24 + (g & 1) * 8);
      const char* vbase = vcur + ((g >= 2) ? 8192 : 0) + c * 32 +
                          ((((g & 1) ^ ((c >> 2) & 1))) << 4);
      __builtin_amdgcn_s_setprio(1);
      #pragma unroll
      for (int dt = 0; dt < 16; dt++) {
        s16x8 vf = *(const s16x8*)(vbase + dt * 512);
        acc[dt] = __builtin_amdgcn_mfma_f32_16x16x32_bf16(pa, vf, acc[dt], 0, 0, 0);
      }
      __builtin_amdgcn_s_setprio(0);
    }
    __syncthreads();
  }
#undef STAGE_K
#undef STAGE_V

  // ---- partial row sums across the 16 c-lanes; write l (this wave's path/rows)
  #pragma unroll
  for (int j = 0; j < 4; j++) {
    #pragma unroll
    for (int off = 1; off < 16; off <<= 1)
      lr[j] += __shfl_xor(lr[j], off);
  }
  const int pqidx = (half * 8 + b) * 36 + qt;
  if (c == 0) {
    #pragma unroll
    for (int j = 0; j < 4; j++)
      lb[path * 36864 + pqidx * 64 + qs * 16 + g * 4 + j] = lr[j];
  }

  // ---- write bf16 partials [256 d][64 q] (this wave: its path, rows qs*16..+15)
  unsigned short* const pdst = (path ? pa2 : pa1) + (size_t)pqidx * 16384;
  float* Ws = (float*)(smem + w * 4352);    // [16][68] wave-private
  const int q = l & 15, ds = l >> 4;
  #pragma unroll
  for (int ch = 0; ch < 4; ch++) {
    #pragma unroll
    for (int dtp = 0; dtp < 4; dtp++) {
      const int dt = ch * 4 + dtp;
      #pragma unroll
      for (int j = 0; j < 4; j++)
        Ws[(g * 4 + j) * 68 + dtp * 16 + c] = acc[dt][j];
    }
    #pragma unroll
    for (int i = 0; i < 16; i++) {
      int d = ch * 64 + i * 4 + ds;
      pdst[d * 64 + qs * 16 + q] = f2bf(Ws[q * 68 + i * 4 + ds]);
    }
  }
}

// ---------------- combine: out = qry + c1*(a1_0+a1_1)/l1 + c2*(a2_0+a2_1)/l2 ----------------
// Grid (288, 2): blockIdx.y selects a 128-d half.
__global__ __launch_bounds__(256)
void combine_kernel(const unsigned short* __restrict__ pa1, const unsigned short* __restrict__ pa2,
                    const float* __restrict__ lb, const float* __restrict__ qry,
                    const float* __restrict__ mup, float* __restrict__ out) {
  const int bid = blockIdx.x;
  const int dh = blockIdx.y;
  const int b = bid & 7, qt = bid >> 3;
  const int t = threadIdx.x;
  const int q = t & 63, dr = t >> 6;
  const size_t bo = (size_t)b * CC * NTOK;
  const int q0 = qt * 64;

  const int i0 = (0 * 8 + b) * 36 + qt;
  const int i1 = (1 * 8 + b) * 36 + qt;
  float l1 = lb[i0 * 64 + q] + lb[i1 * 64 + q];
  float l2 = lb[36864 + i0 * 64 + q] + lb[36864 + i1 * 64 + q];
  const float mu = mup[0];
  const float w1 = 0.5f / (0.5f + mu) / l1;
  const float w2 = mu / (0.5f + mu) / l2;

  const unsigned short* p10 = pa1 + (size_t)i0 * 16384;
  const unsigned short* p11 = pa1 + (size_t)i1 * 16384;
  const unsigned short* p20 = pa2 + (size_t)i0 * 16384;
  const unsigned short* p21 = pa2 + (size_t)i1 * 16384;

  #pragma unroll
  for (int i = 0; i < 32; i++) {
    int d = dh * 128 + dr * 32 + i;
    int off = d * 64 + q;
    float av1 = bf2f(p10[off]) + bf2f(p11[off]);
    float av2 = bf2f(p20[off]) + bf2f(p21[off]);
    size_t gi = bo + (size_t)d * NTOK + q0 + q;
    out[gi] = qry[gi] + av1 * w1 + av2 * w2;
  }
}

extern "C" void kernel_launch(void* const* d_in, const int* in_sizes, int n_in,
                              void* d_out, int out_size, void* d_ws, size_t ws_size,
                              hipStream_t stream) {
  const float* qry  = (const float*)d_in[0];
  const float* mask = (const float*)d_in[1];
  const float* fts  = (const float*)d_in[2];
  const float* Wq   = (const float*)d_in[3];
  const float* Wk   = (const float*)d_in[4];
  const float* Wv   = (const float*)d_in[5];
  const float* mu   = (const float*)d_in[6];
  float* out = (float*)d_out;

  const size_t SZ = (size_t)BB * CC * NTOK;          // 4,718,592
  unsigned short* base = (unsigned short*)d_ws;
  unsigned short* PA1 = base;                        // overlays Xt (dead by attn)
  unsigned short* PA2 = base + 9437184;
  float*          LB  = (float*)(base + 18874368);
  unsigned short* Xtq = base;
  unsigned short* Xtm = base + SZ;
  unsigned short* Xtf = base + 2 * SZ;
  unsigned short* Qw  = base + 19169280;
  unsigned short* K1w = Qw + SZ;
  unsigned short* K2w = Qw + 2 * SZ;
  unsigned short* Vtw = Qw + 3 * SZ;
  unsigned short* Wqh = Qw + 4 * SZ;
  unsigned short* Wkh = Wqh + CC * CC;
  unsigned short* Wvh = Wkh + CC * CC;

  prep_kernel<<<dim3(NTOK / 64, CC / 64, 25), 256, 0, stream>>>(
      qry, mask, fts, Xtq, Xtm, Xtf, Wq, Wk, Wv, Wqh, Wkh, Wvh);

  const int GG = BB * (NTOK / 64);                   // 288
  gemm_kernel<<<dim3(GG, 4), 256, 0, stream>>>(Xtq, Xtm, Xtf, Wqh, Wkh, Wvh,
                                               Qw, K1w, K2w, Vtw);

  attn_kernel<<<2 * GG, 512, 0, stream>>>(Qw, K1w, K2w, Vtw, PA1, PA2, LB);
  combine_kernel<<<dim3(GG, 2), 256, 0, stream>>>(PA1, PA2, LB, qry, mu, out);
}

// Round 18
// 226.837 us; speedup vs baseline: 1.8784x; 1.8784x over previous
//
#include <hip/hip_runtime.h>
#include <math.h>

#define BB 8
#define CC 256
#define NTOK 2304   // 48*48
#define NPL 36      // 32-token pairs per k-half (split-K factor 2)
#define LOG2E 1.4426950408889634f
#define BIAS2 72.134752f   // p = 2^(s-BIAS2): overflow-free no-max softmax

typedef __attribute__((ext_vector_type(4))) float f32x4;
typedef __attribute__((ext_vector_type(8))) short s16x8;
typedef __attribute__((ext_vector_type(4))) short s16x4;

__device__ inline unsigned short f2bf(float x) {
  unsigned u = __builtin_bit_cast(unsigned, x);
  return (unsigned short)((u + 0x7FFFu + ((u >> 16) & 1u)) >> 16);
}
__device__ inline float bf2f(unsigned short h) {
  return __builtin_bit_cast(float, (unsigned)h << 16);
}
__device__ inline unsigned short f2h(float x) {
  _Float16 h = (_Float16)x;
  return __builtin_bit_cast(unsigned short, h);
}

// async global -> LDS, 16B/lane; LDS dst = wave-uniform base + lane*16
__device__ inline void async16(void* lds, const void* g) {
  __builtin_amdgcn_global_load_lds(
      (const __attribute__((address_space(1))) unsigned int*)g,
      (__attribute__((address_space(3))) unsigned int*)lds, 16, 0, 0);
}

// ---------------- prepass: X[c][n] fp32 -> Xt[n][c] fp16 (z<24); W conv (z==24) ----------------
__global__ __launch_bounds__(256)
void prep_kernel(const float* __restrict__ X0, const float* __restrict__ X1,
                 const float* __restrict__ X2, unsigned short* __restrict__ Y0,
                 unsigned short* __restrict__ Y1, unsigned short* __restrict__ Y2,
                 const float* __restrict__ W0, const float* __restrict__ W1,
                 const float* __restrict__ W2, unsigned short* __restrict__ Wh0,
                 unsigned short* __restrict__ Wh1, unsigned short* __restrict__ Wh2) {
  __shared__ float Ls[64][65];
  const int t = threadIdx.x;
  const int z = blockIdx.z;

  if (z == 24) {
    int idx = (blockIdx.x * 4 + blockIdx.y) * 256 + t;     // 0..36863
    for (int e = idx; e < 49152; e += 36864) {
      int m = e / 16384, r = e - m * 16384;
      const float* s = (m == 0) ? W0 : (m == 1) ? W1 : W2;
      unsigned short* d = (m == 0) ? Wh0 : (m == 1) ? Wh1 : Wh2;
      f32x4 v = *(const f32x4*)(s + r * 4);
      s16x4 o;
      #pragma unroll
      for (int i = 0; i < 4; i++) o[i] = (short)f2h(v[i]);
      *(s16x4*)(d + r * 4) = o;
    }
    return;
  }

  const int n0 = blockIdx.x * 64, c0 = blockIdx.y * 64;
  const int src = z >> 3, b = z & 7;
  const float* X = (src == 0) ? X0 : (src == 1) ? X1 : X2;
  unsigned short* Y = (src == 0) ? Y0 : (src == 1) ? Y1 : Y2;
  const float* Xb = X + (size_t)b * CC * NTOK;
  unsigned short* Yb = Y + (size_t)b * CC * NTOK;

  #pragma unroll
  for (int rr = 0; rr < 16; rr++) {
    int cl = rr * 4 + (t >> 6);
    Ls[cl][t & 63] = Xb[(size_t)(c0 + cl) * NTOK + n0 + (t & 63)];
  }
  __syncthreads();
  #pragma unroll
  for (int rr = 0; rr < 8; rr++) {
    int nl = rr * 8 + (t >> 5);
    int cl = (t & 31) * 2;
    unsigned v = (unsigned)f2h(Ls[cl][nl]) | ((unsigned)f2h(Ls[cl + 1][nl]) << 16);
    *(unsigned*)((char*)Yb + ((size_t)(n0 + nl) * CC + c0 + cl) * 2) = v;
  }
}

// ---------------- fused MFMA projection GEMM (all 4 projections, one dispatch) ----------------
// blockIdx.y = m: 0 -> Q (scale LOG2E, fp16 [n][d]); 1 -> K1; 2 -> K2 (fp16 [n][d]);
// 3 -> V (bf16 Vt [d][n]). Block-uniform branches only.
__global__ __launch_bounds__(256, 2)
void gemm_kernel(const unsigned short* __restrict__ Xtq, const unsigned short* __restrict__ Xtm,
                 const unsigned short* __restrict__ Xtf, const unsigned short* __restrict__ Wqh,
                 const unsigned short* __restrict__ Wkh, const unsigned short* __restrict__ Wvh,
                 unsigned short* __restrict__ Qw, unsigned short* __restrict__ K1w,
                 unsigned short* __restrict__ K2w, unsigned short* __restrict__ Vtw) {
  __shared__ alignas(16) char smem[32768];

  const int m = blockIdx.y;
  const unsigned short* Xt = (m == 0) ? Xtq : (m == 2) ? Xtm : Xtf;
  const unsigned short* Wh = (m == 0) ? Wqh : (m == 3) ? Wvh : Wkh;
  unsigned short* Y = (m == 0) ? Qw : (m == 1) ? K1w : (m == 2) ? K2w : Vtw;

  const int t = threadIdx.x;
  const int w = t >> 6, l = t & 63, g = l >> 4, c = l & 15;
  const int bid = blockIdx.x;
  const int b = bid & 7, nt = bid >> 3;
  const int n0w = nt * 64 + w * 16;
  const size_t bo = (size_t)b * CC * NTOK;

  const char* Xb = (const char*)(Xt + bo);
  const char* Wb = (const char*)Wh;
  char* Yb = (char*)(Y + bo);

  int koff[4], cdst[4];
  #pragma unroll
  for (int j = 0; j < 4; j++) {
    int ck = w + 4 * j;
    int row = ck * 2 + (l >> 5);
    koff[j] = row * 512 + (((l & 31) * 16) ^ ((row & 7) << 4));
    cdst[j] = ck * 1024 + l * 16;
  }
  int kxor[8];
  #pragma unroll
  for (int dc = 0; dc < 8; dc++)
    kxor[dc] = (dc * 64 + g * 16) ^ ((c & 7) << 4);

  s16x8 xa[8];
  #pragma unroll
  for (int dc = 0; dc < 8; dc++)
    xa[dc] = *(const s16x8*)(Xb + (n0w + c) * 512 + dc * 64 + g * 16);

  f32x4 acc[16];

#define STAGE_W(WB, TILE)                                            \
  do {                                                               \
    _Pragma("unroll")                                                \
    for (int j_ = 0; j_ < 4; j_++)                                   \
      async16((WB) + cdst[j_], Wb + (TILE) * 16384 + koff[j_]);      \
  } while (0)

  STAGE_W(smem, 0);
  __syncthreads();

  #pragma unroll
  for (int ph = 0; ph < 8; ph++) {
    char* cur = smem + (ph & 1) * 16384;
    if (ph < 7) STAGE_W(smem + ((ph & 1) ^ 1) * 16384, ph + 1);
    __builtin_amdgcn_s_setprio(1);
    #pragma unroll
    for (int s = 0; s < 2; s++) {
      const char* Kt = cur + (s * 16 + c) * 512;
      f32x4 sx[2] = {(f32x4){0.f, 0.f, 0.f, 0.f}, (f32x4){0.f, 0.f, 0.f, 0.f}};
      #pragma unroll
      for (int dc = 0; dc < 8; dc++) {
        s16x8 wf = *(const s16x8*)(Kt + kxor[dc]);
        sx[dc >> 2] = __builtin_amdgcn_mfma_f32_16x16x32_f16(xa[dc], wf, sx[dc >> 2], 0, 0, 0);
      }
      acc[ph * 2 + s] = sx[0] + sx[1];
    }
    __builtin_amdgcn_s_setprio(0);
    __syncthreads();
  }
#undef STAGE_W

  if (m != 3) {
    unsigned short* Ws = (unsigned short*)(smem + w * 8192);   // [16][256]
    const float scale = (m == 0) ? LOG2E : 1.0f;
    #pragma unroll
    for (int dt = 0; dt < 16; dt++)
      #pragma unroll
      for (int j = 0; j < 4; j++)
        Ws[(g * 4 + j) * 256 + dt * 16 + c] = f2h(acc[dt][j] * scale);
    #pragma unroll
    for (int r = 0; r < 16; r++) {
      s16x4 v = *(const s16x4*)&Ws[r * 256 + l * 4];
      *(s16x4*)(Yb + (size_t)(n0w + r) * 512 + l * 8) = v;
    }
  } else {
    unsigned short* Vs = (unsigned short*)(smem + w * 8192);   // [16][20]
    #pragma unroll
    for (int dt = 0; dt < 16; dt++) {
      s16x4 pv;
      #pragma unroll
      for (int j = 0; j < 4; j++) pv[j] = (short)f2bf(acc[dt][j]);
      *(s16x4*)&Vs[c * 20 + g * 4] = pv;
      s16x4 vv = *(const s16x4*)&Vs[(l >> 2) * 20 + (l & 3) * 4];
      *(s16x4*)(Yb + (size_t)(dt * 16 + (l >> 2)) * 4608 + (size_t)(n0w + (l & 3) * 4) * 2) = vv;
    }
  }
}

// ---------------- fused dual-softmax MFMA attention, split-K, path-specialized ----------------
// (R11/R14/R16 structure verbatim — 185 us known-good. Grid 576: (b, qt, half).
// 4 waves = 2 paths x 2 q-strips of 32 rows; kf/vf loaded once, used twice.)
__global__ __launch_bounds__(256, 2)
void attn_kernel(const unsigned short* __restrict__ Qf, const unsigned short* __restrict__ K1,
                 const unsigned short* __restrict__ K2, const unsigned short* __restrict__ Vt,
                 unsigned short* __restrict__ pa1, unsigned short* __restrict__ pa2,
                 float* __restrict__ lb) {
  __shared__ alignas(16) char smem[77824];
  char* const kb0 = smem;
  char* const kb1 = smem + 16384;

  const int t = threadIdx.x;
  const int w = t >> 6, l = t & 63, g = l >> 4, c = l & 15;
  const int path = w >> 1, qs = w & 1;
  const int bid = blockIdx.x;
  const int b = bid & 7;                    // batch -> XCD pin
  const int r0 = bid >> 3;                  // 0..71
  const int qt = r0 % 36, half = r0 / 36;
  const int q0 = qt * 64 + qs * 32;         // this wave's 32 q-rows
  const size_t bo = (size_t)b * CC * NTOK;

  const char* Qb  = (const char*)(Qf + bo);
  const char* K1b = (const char*)(K1 + bo);
  const char* K2b = (const char*)(K2 + bo);
  const char* Vtb = (const char*)(Vt + bo);

  unsigned short* const Pe  = (unsigned short*)(smem + 65536 + w * 3072);
  unsigned short* const Pod = Pe + 768;

  int koff[2], voff[2], cdst[2];
  #pragma unroll
  for (int j = 0; j < 2; j++) {
    int ck = w + 4 * j;
    int tok = ck * 2 + (l >> 5);
    koff[j] = tok * 512 + (((l & 31) * 16) ^ ((tok & 7) << 4));
    voff[j] = (ck * 32 + (l >> 1)) * 4608 + (((l & 1) ^ ((l >> 3) & 1)) << 4);
    cdst[j] = ck * 1024 + l * 16;
  }

  int kxor[8];
  #pragma unroll
  for (int dc = 0; dc < 8; dc++)
    kxor[dc] = (dc * 64 + g * 16) ^ ((c & 7) << 4);

  // Q fp16 fragments: 2 strips x 8 dc (strip st -> rows q0+st*16)
  s16x8 qf[2][8];
  #pragma unroll
  for (int st = 0; st < 2; st++)
    #pragma unroll
    for (int dc = 0; dc < 8; dc++)
      qf[st][dc] = *(const s16x8*)(Qb + (q0 + st * 16 + c) * 512 + dc * 64 + g * 16);

  f32x4 a0[16], a1r[16];                    // strip 0 / strip 1 accumulators
  #pragma unroll
  for (int dt = 0; dt < 16; dt++) {
    a0[dt]  = (f32x4){0.f, 0.f, 0.f, 0.f};
    a1r[dt] = (f32x4){0.f, 0.f, 0.f, 0.f};
  }
  float lr[2][4] = {{0.f, 0.f, 0.f, 0.f}, {0.f, 0.f, 0.f, 0.f}};

#define STAGE_K(KB, TILE)                                                  \
  do {                                                                     \
    _Pragma("unroll")                                                      \
    for (int pp_ = 0; pp_ < 2; pp_++) {                                    \
      const char* ks_ = (pp_ ? K2b : K1b) + (size_t)(TILE) * 8192;         \
      async16((KB) + pp_ * 8192 + cdst[0], ks_ + koff[0]);                 \
      async16((KB) + pp_ * 8192 + cdst[1], ks_ + koff[1]);                 \
    }                                                                      \
  } while (0)

#define STAGE_V(VB, PAIR)                                                  \
  do {                                                                     \
    _Pragma("unroll")                                                      \
    for (int h_ = 0; h_ < 2; h_++) {                                       \
      const char* vs_ = Vtb + (PAIR) * 64 + h_ * 32;                       \
      async16((VB) + h_ * 8192 + cdst[0], vs_ + voff[0]);                  \
      async16((VB) + h_ * 8192 + cdst[1], vs_ + voff[1]);                  \
    }                                                                      \
  } while (0)

  const int tb = half * 72;                 // k-tile base for this half
  const int pb = half * 36;                 // V pair base

  STAGE_K(kb0, tb);
  STAGE_V(smem + 32768, pb);
  __syncthreads();

  for (int p = 0; p < NPL; p++) {
    char* vcur = smem + 32768 + (p & 1) * 16384;
    char* vnxt = smem + 32768 + ((p & 1) ^ 1) * 16384;

    // ======== even phase: tile tb+2p from kb0 (this wave's path only) ========
    STAGE_K(kb1, tb + 2 * p + 1);
    {
      const char* Kt = kb0 + path * 8192 + c * 512;
      f32x4 s0 = (f32x4){0.f, 0.f, 0.f, 0.f};
      f32x4 s1 = (f32x4){0.f, 0.f, 0.f, 0.f};
      __builtin_amdgcn_s_setprio(1);
      #pragma unroll
      for (int dc = 0; dc < 8; dc++) {
        s16x8 kf = *(const s16x8*)(Kt + kxor[dc]);   // loaded once, used twice
        s0 = __builtin_amdgcn_mfma_f32_16x16x32_f16(qf[0][dc], kf, s0, 0, 0, 0);
        s1 = __builtin_amdgcn_mfma_f32_16x16x32_f16(qf[1][dc], kf, s1, 0, 0, 0);
      }
      __builtin_amdgcn_s_setprio(0);
      #pragma unroll
      for (int j = 0; j < 4; j++) {
        float pv = exp2f(s0[j] - BIAS2);
        lr[0][j] += pv;
        Pe[(g * 4 + j) * 24 + c] = f2bf(pv);
        float pw = exp2f(s1[j] - BIAS2);
        lr[1][j] += pw;
        Pe[(16 + g * 4 + j) * 24 + c] = f2bf(pw);
      }
    }
    __syncthreads();

    // ======== odd phase: tile tb+2p+1 from kb1, PV on vcur ========
    if (p + 1 < NPL) {
      STAGE_K(kb0, tb + 2 * p + 2);
      STAGE_V(vnxt, pb + p + 1);
    }
    {
      const char* Kt = kb1 + path * 8192 + c * 512;
      f32x4 s0 = (f32x4){0.f, 0.f, 0.f, 0.f};
      f32x4 s1 = (f32x4){0.f, 0.f, 0.f, 0.f};
      __builtin_amdgcn_s_setprio(1);
      #pragma unroll
      for (int dc = 0; dc < 8; dc++) {
        s16x8 kf = *(const s16x8*)(Kt + kxor[dc]);
        s0 = __builtin_amdgcn_mfma_f32_16x16x32_f16(qf[0][dc], kf, s0, 0, 0, 0);
        s1 = __builtin_amdgcn_mfma_f32_16x16x32_f16(qf[1][dc], kf, s1, 0, 0, 0);
      }
      __builtin_amdgcn_s_setprio(0);
      #pragma unroll
      for (int j = 0; j < 4; j++) {
        float pv = exp2f(s0[j] - BIAS2);
        lr[0][j] += pv;
        Pod[(g * 4 + j) * 24 + c] = f2bf(pv);
        float pw = exp2f(s1[j] - BIAS2);
        lr[1][j] += pw;
        Pod[(16 + g * 4 + j) * 24 + c] = f2bf(pw);
      }
    }
    {
      // paired A-frags per strip: g<2 lanes -> even tile, g>=2 -> odd tile
      s16x8 pa0 = *(const s16x8*)(((g < 2) ? Pe : Pod) + (c) * 24 + (g & 1) * 8);
      s16x8 pa1 = *(const s16x8*)(((g < 2) ? Pe : Pod) + (16 + c) * 24 + (g & 1) * 8);
      const char* vbase = vcur + ((g >= 2) ? 8192 : 0) + c * 32 +
                          ((((g & 1) ^ ((c >> 2) & 1))) << 4);
      __builtin_amdgcn_s_setprio(1);
      #pragma unroll
      for (int dt = 0; dt < 16; dt++) {
        s16x8 vf = *(const s16x8*)(vbase + dt * 512);   // loaded once, used twice
        a0[dt]  = __builtin_amdgcn_mfma_f32_16x16x32_bf16(pa0, vf, a0[dt], 0, 0, 0);
        a1r[dt] = __builtin_amdgcn_mfma_f32_16x16x32_bf16(pa1, vf, a1r[dt], 0, 0, 0);
      }
      __builtin_amdgcn_s_setprio(0);
    }
    __syncthreads();
  }
#undef STAGE_K
#undef STAGE_V

  // ---- partial row sums across the 16 c-lanes; write l (this wave's path/rows)
  #pragma unroll
  for (int st = 0; st < 2; st++)
    #pragma unroll
    for (int j = 0; j < 4; j++) {
      #pragma unroll
      for (int off = 1; off < 16; off <<= 1)
        lr[st][j] += __shfl_xor(lr[st][j], off);
    }
  const int pqidx = (half * 8 + b) * 36 + qt;
  if (c == 0) {
    #pragma unroll
    for (int st = 0; st < 2; st++)
      #pragma unroll
      for (int j = 0; j < 4; j++)
        lb[path * 36864 + pqidx * 64 + qs * 32 + st * 16 + g * 4 + j] = lr[st][j];
  }

  // ---- write bf16 partials [256 d][64 q] (this wave: its path, rows qs*32..+31)
  unsigned short* const pdst = (path ? pa2 : pa1) + (size_t)pqidx * 16384;
  float* Ws = (float*)(smem + w * 4352);
  const int q = l & 15, ds = l >> 4;
  #pragma unroll
  for (int st = 0; st < 2; st++) {
    const f32x4* ap = st ? a1r : a0;
    #pragma unroll
    for (int ch = 0; ch < 4; ch++) {
      #pragma unroll
      for (int dtp = 0; dtp < 4; dtp++) {
        const int dt = ch * 4 + dtp;
        #pragma unroll
        for (int j = 0; j < 4; j++)
          Ws[(g * 4 + j) * 68 + dtp * 16 + c] = ap[dt][j];
      }
      #pragma unroll
      for (int i = 0; i < 16; i++) {
        int d = ch * 64 + i * 4 + ds;
        pdst[d * 64 + qs * 32 + st * 16 + q] = f2bf(Ws[q * 68 + i * 4 + ds]);
      }
    }
  }
}

// ---------------- combine: out = qry + c1*(a1_0+a1_1)/l1 + c2*(a2_0+a2_1)/l2 ----------------
// Grid (288, 2): blockIdx.y selects a 128-d half (halves the makespan tail).
__global__ __launch_bounds__(256)
void combine_kernel(const unsigned short* __restrict__ pa1, const unsigned short* __restrict__ pa2,
                    const float* __restrict__ lb, const float* __restrict__ qry,
                    const float* __restrict__ mup, float* __restrict__ out) {
  const int bid = blockIdx.x;
  const int dh = blockIdx.y;
  const int b = bid & 7, qt = bid >> 3;
  const int t = threadIdx.x;
  const int q = t & 63, dr = t >> 6;
  const size_t bo = (size_t)b * CC * NTOK;
  const int q0 = qt * 64;

  const int i0 = (0 * 8 + b) * 36 + qt;
  const int i1 = (1 * 8 + b) * 36 + qt;
  float l1 = lb[i0 * 64 + q] + lb[i1 * 64 + q];
  float l2 = lb[36864 + i0 * 64 + q] + lb[36864 + i1 * 64 + q];
  const float mu = mup[0];
  const float w1 = 0.5f / (0.5f + mu) / l1;
  const float w2 = mu / (0.5f + mu) / l2;

  const unsigned short* p10 = pa1 + (size_t)i0 * 16384;
  const unsigned short* p11 = pa1 + (size_t)i1 * 16384;
  const unsigned short* p20 = pa2 + (size_t)i0 * 16384;
  const unsigned short* p21 = pa2 + (size_t)i1 * 16384;

  #pragma unroll
  for (int i = 0; i < 32; i++) {
    int d = dh * 128 + dr * 32 + i;
    int off = d * 64 + q;
    float av1 = bf2f(p10[off]) + bf2f(p11[off]);
    float av2 = bf2f(p20[off]) + bf2f(p21[off]);
    size_t gi = bo + (size_t)d * NTOK + q0 + q;
    out[gi] = qry[gi] + av1 * w1 + av2 * w2;
  }
}

extern "C" void kernel_launch(void* const* d_in, const int* in_sizes, int n_in,
                              void* d_out, int out_size, void* d_ws, size_t ws_size,
                              hipStream_t stream) {
  const float* qry  = (const float*)d_in[0];
  const float* mask = (const float*)d_in[1];
  const float* fts  = (const float*)d_in[2];
  const float* Wq   = (const float*)d_in[3];
  const float* Wk   = (const float*)d_in[4];
  const float* Wv   = (const float*)d_in[5];
  const float* mu   = (const float*)d_in[6];
  float* out = (float*)d_out;

  const size_t SZ = (size_t)BB * CC * NTOK;          // 4,718,592
  unsigned short* base = (unsigned short*)d_ws;
  // partial region [0, 19169280) shorts — overlays the Xt buffers (dead by attn time)
  unsigned short* PA1 = base;                        // 2*8*36*16384 = 9,437,184
  unsigned short* PA2 = base + 9437184;
  float*          LB  = (float*)(base + 18874368);   // 73,728 f32
  unsigned short* Xtq = base;                        // prep/gemm-phase only
  unsigned short* Xtm = base + SZ;
  unsigned short* Xtf = base + 2 * SZ;
  unsigned short* Qw  = base + 19169280;
  unsigned short* K1w = Qw + SZ;
  unsigned short* K2w = Qw + 2 * SZ;
  unsigned short* Vtw = Qw + 3 * SZ;
  unsigned short* Wqh = Qw + 4 * SZ;
  unsigned short* Wkh = Wqh + CC * CC;
  unsigned short* Wvh = Wkh + CC * CC;

  prep_kernel<<<dim3(NTOK / 64, CC / 64, 25), 256, 0, stream>>>(
      qry, mask, fts, Xtq, Xtm, Xtf, Wq, Wk, Wv, Wqh, Wkh, Wvh);

  const int GG = BB * (NTOK / 64);                   // 288
  gemm_kernel<<<dim3(GG, 4), 256, 0, stream>>>(Xtq, Xtm, Xtf, Wqh, Wkh, Wvh,
                                               Qw, K1w, K2w, Vtw);

  attn_kernel<<<2 * GG, 256, 0, stream>>>(Qw, K1w, K2w, Vtw, PA1, PA2, LB);
  combine_kernel<<<dim3(GG, 2), 256, 0, stream>>>(PA1, PA2, LB, qry, mu, out);
}